// Round 4
// baseline (198.073 us; speedup 1.0000x reference)
//
#include <hip/hip_runtime.h>
#include <math.h>

// CTC forward (keras ctc_batch_cost), B=1024 T=256 C=128 L=64, S=129.
// R9: register-resident deep pipeline. No LDS at all.
//  - Each wave streams its y_pred row as 32 chunks of 4 KB; each chunk is
//    4 x global_load_dwordx4 (float4, 1 KB/instr) into a 14-slot register
//    ring (224 VGPRs). 14 chunks = 56 KB/wave in flight (vs 28 KB for the
//    old LDS ring, which was capped by 160 KB/CU LDS at depth 7-9).
//    Slack per chunk rises from 5 slots to 14 -> BW*latency tolerance 2.6x.
//  - q-gather: lane l holds classes 4(l%32)..+3 of row 2k+(l>=32) in
//    buf[s][k]. ql via 4 x ds_bpermute + 2-level cndmask (index li&3);
//    blank prob = readlane(v.w, 31|63) -> scalar, free broadcast.
//  - No manual vmcnt: compiler tracks VGPR load deps exactly. sched_barrier
//    pins each slot's issue cluster before the gather/compute.
//  - Probability-domain semiring recurrence with x128 bias and wave-uniform
//    renorm every 8 steps (exponent stripped into Esum) -- verified absmax 0.
//  - All register-ring indices are compile-time constants via full unroll
//    of the 32-slot loop (runtime-indexed VGPR arrays would spill).

#define Bn 1024
#define Tn 256
#define Cn 128
#define Ln 64
#define BLANK 127
#define U 8
#define NCH (Tn / U)      // 32 chunks
#define DEPTH 14          // register ring slots: 56 loads in flight <= 63
#define EPS128 (1e-7f * 128.0f)
#define LN2 0.69314718055994530942f

#define SCHED_FENCE() __builtin_amdgcn_sched_barrier(0)

template <int CTRL>
__device__ __forceinline__ float dpp_movf(float x) {
    return __int_as_float(__builtin_amdgcn_update_dpp(
        0, __float_as_int(x), CTRL, 0xF, 0xF, true));
}
__device__ __forceinline__ int dpp_shr1_i(int x) {
    return __builtin_amdgcn_update_dpp(0, x, 0x138, 0xF, 0xF, true);
}

__global__ __launch_bounds__(64)
void ctc_reg_kernel(const int* __restrict__ y_true,
                    const float* __restrict__ y_pred,
                    float* __restrict__ out) {
    const int b = blockIdx.x;
    const int i = threadIdx.x;

    const int li = y_true[b * Ln + i];
    const int ll = dpp_shr1_i(li);                 // lab[i-1] (lane0 -> 0)
    const float skf = (li != ll) ? 1.0f : 0.0f;
    const bool sel0 = (li & 1) != 0;               // class & 1
    const bool sel1 = (li & 2) != 0;               // class & 2
    const int idx0 = (li >> 2) << 2;               // bpermute byte index, h=0

    const float* gb = y_pred + (size_t)b * (Tn * Cn);

    float4 buf[DEPTH][4];                          // 224 VGPRs of stream data

    auto issue = [&](int c) {
        const int s = c % DEPTH;                   // constant after unroll
        const float* g = gb + c * (U * Cn);
#pragma unroll
        for (int k = 0; k < 4; ++k)                // 4 x 1KB = 4 KB chunk
            buf[s][k] = *reinterpret_cast<const float4*>(g + k * 256 + i * 4);
    };

    // lane l, instr k: classes 4(l%32)+e of row 2k+(l>=32).
    // row j = 2k+h: src lane = 32h + (li>>2), element = li&3.
    auto gatherq = [&](int c, float* ql, float* qb) {
        const int s = c % DEPTH;                   // constant after unroll
#pragma unroll
        for (int j = 0; j < U; ++j) {
            const int k = j >> 1;
            const int h = j & 1;
            const int sl4 = idx0 + (h << 7);       // (32h + (li>>2)) * 4
            const float4 v = buf[s][k];
            const int a0 = __builtin_amdgcn_ds_bpermute(sl4, __float_as_int(v.x));
            const int a1 = __builtin_amdgcn_ds_bpermute(sl4, __float_as_int(v.y));
            const int a2 = __builtin_amdgcn_ds_bpermute(sl4, __float_as_int(v.z));
            const int a3 = __builtin_amdgcn_ds_bpermute(sl4, __float_as_int(v.w));
            const float g01 = sel0 ? __int_as_float(a1) : __int_as_float(a0);
            const float g23 = sel0 ? __int_as_float(a3) : __int_as_float(a2);
            const float g = sel1 ? g23 : g01;
            ql[j] = fmaf(g, 128.0f, EPS128);
            const float bl = __int_as_float(
                __builtin_amdgcn_readlane(__float_as_int(v.w), 31 + (h << 5)));
            qb[j] = fmaf(bl, 128.0f, EPS128);      // class 127 (blank)
        }
    };

    float E = 0.f, O = 0.f, X = 0.f;   // states 2i, 2i+1, 128(lane63)
    int Esum = 0;

    auto steps = [&](const float* ql, const float* qb, bool first) {
#pragma unroll
        for (int j = 0; j < U; ++j) {
            if (first && j == 0) {                 // t=0: only states 0,1
                E = (i == 0) ? qb[0] : 0.f;
                O = (i == 0) ? ql[0] : 0.f;
                X = 0.f;
                continue;
            }
            const float Ol = dpp_movf<0x138>(O);   // state 2i-1 from left
            const float t1 = O + E;
            const float nO = fmaf(skf, Ol, t1) * ql[j];
            const float nE = (E + Ol) * qb[j];
            const float nX = (X + O) * qb[j];
            E = nE; O = nO; X = nX;
        }
    };
    auto renorm = [&]() {
        float m = fmaxf(E, O);
        if (i == 63) m = fmaxf(m, X);
        m = fmaxf(m, dpp_movf<0x111>(m));
        m = fmaxf(m, dpp_movf<0x112>(m));
        m = fmaxf(m, dpp_movf<0x114>(m));
        m = fmaxf(m, dpp_movf<0x118>(m));
        m = fmaxf(m, dpp_movf<0x142>(m));
        m = fmaxf(m, dpp_movf<0x143>(m));          // lane63 = wave max
        const unsigned ub =
            (unsigned)__builtin_amdgcn_readlane(__float_as_int(m), 63);
        const int eb = (int)(ub >> 23);
        const float sc = __int_as_float((unsigned)(254 - eb) << 23);
        Esum += eb - 127;
        E *= sc; O *= sc; X *= sc;
    };

    // ---- prologue: fill the register pipe (chunks 0..13 in flight) ----
#pragma unroll
    for (int c = 0; c < DEPTH; ++c) issue(c);
    SCHED_FENCE();

    float qlv[2][U], qbv[2][U];                    // parity double-buffer
    gatherq(0, qlv[0], qbv[0]);

    // ---- 32 slots, fully unrolled (static register-ring indices) ----
#pragma unroll
    for (int cc = 0; cc < NCH; ++cc) {
        if (cc + DEPTH < NCH) {                    // keep 14 chunks in flight
            issue(cc + DEPTH);
            SCHED_FENCE();
        }
        if (cc + 1 < NCH)                          // q one chunk ahead
            gatherq(cc + 1, qlv[(cc + 1) & 1], qbv[(cc + 1) & 1]);
        steps(qlv[cc & 1], qbv[cc & 1], cc == 0);
        if (cc != NCH - 1) renorm();
    }

    if (i == 63) {
        const float s = O + X;       // alpha[127] + alpha[128] (scaled)
#if __has_builtin(__builtin_amdgcn_logf)
        const float l2 = __builtin_amdgcn_logf(s);
#else
        const float l2 = log2f(s);
#endif
        out[b] = -(l2 + (float)(Esum - 7 * Tn)) * LN2;
    }
}

extern "C" void kernel_launch(void* const* d_in, const int* in_sizes, int n_in,
                              void* d_out, int out_size, void* d_ws, size_t ws_size,
                              hipStream_t stream) {
    const int*   y_true = (const int*)d_in[0];
    const float* y_pred = (const float*)d_in[1];
    float*       out    = (float*)d_out;
    hipLaunchKernelGGL(ctc_reg_kernel, dim3(Bn), dim3(64), 0, stream,
                       y_true, y_pred, out);
}

// Round 5
// 194.042 us; speedup vs baseline: 1.0208x; 1.0208x over previous
//
#include <hip/hip_runtime.h>
#include <math.h>

// CTC forward (keras ctc_batch_cost), B=1024 T=256 C=128 L=64, S=129.
// R10: split-T wave pairing. Two wave64s per batch element: wave w owns
// chunks c with (c&1)==w (16 x 4KB each), streamed through its own 4-deep
// LDS ring. 1024 blocks x 128 thr = 2048 waves = 8 waves/CU (2/SIMD) --
// doubling the number of concurrent HBM load streams, which R5/R9 showed
// is the only untested lever (per-wave read rate pinned at ~3.4 GB/s
// regardless of pipeline depth 7 or 14).
// The serial recurrence ping-pongs between the waves each chunk; the
// non-owner gathers its next chunk's q-values (16 ds_reads) off the
// critical path while the owner computes. State (E,O,X per lane, Esum)
// hands off via LDS around raw s_barrier + lgkmcnt(0) ONLY -- never
// __syncthreads(), which drains vmcnt(0) and would collapse the pipeline.
// Per-wave vmcnt ledger: prologue 16 out; steady non-owner wait 12;
// tail waits 8/4/0 as issuance stops at chunk 15.
//  - Probability-domain semiring recurrence, x128 bias, renorm per chunk
//    (exponent stripped into Esum, carried through the handoff).

#define Bn 1024
#define Tn 256
#define Cn 128
#define Ln 64
#define BLANK 127
#define U 8
#define KH 16             // chunks per wave
#define RING 4
#define EPS128 (1e-7f * 128.0f)
#define LN2 0.69314718055994530942f

// s_waitcnt imm: vmcnt bits [3:0]+[15:14]; expcnt[6:4]; lgkmcnt[11:8]
#define WAIT_VM(n) __builtin_amdgcn_s_waitcnt((((n) & 0xF) | (((n) >> 4) << 14)) | 0x0F70)
#define WAIT_LGKM() __builtin_amdgcn_s_waitcnt(0xC07F)   // lgkmcnt(0), vm/exp don't-care
#define SCHED_FENCE() __builtin_amdgcn_sched_barrier(0)

template <int CTRL>
__device__ __forceinline__ float dpp_movf(float x) {
    return __int_as_float(__builtin_amdgcn_update_dpp(
        0, __float_as_int(x), CTRL, 0xF, 0xF, true));
}
__device__ __forceinline__ int dpp_shr1_i(int x) {
    return __builtin_amdgcn_update_dpp(0, x, 0x138, 0xF, 0xF, true);
}
__device__ __forceinline__ void dma16(const float* g, float* l) {
    __builtin_amdgcn_global_load_lds(
        (const __attribute__((address_space(1))) void*)g,
        (__attribute__((address_space(3))) void*)l, 16, 0, 0);
}
__device__ __forceinline__ void wave_sync() {
    SCHED_FENCE();
    WAIT_LGKM();                      // ds_writes visible before barrier
    __builtin_amdgcn_s_barrier();
    SCHED_FENCE();                    // nothing crosses the barrier
}

__global__ __launch_bounds__(128)
void ctc_pair_kernel(const int* __restrict__ y_true,
                     const float* __restrict__ y_pred,
                     float* __restrict__ out) {
    __shared__ __align__(16) float ring[2][RING][U * Cn];   // 32 KB
    __shared__ float stE[64], stO[64], stX[64];
    __shared__ int stS;

    const int w = threadIdx.x >> 6;                // wave id (0/1)
    const int i = threadIdx.x & 63;                // lane
    const int b = blockIdx.x;

    const int li = y_true[b * Ln + i];
    const int ll = dpp_shr1_i(li);                 // lab[i-1] (lane0 -> 0)
    const float skf = (li != ll) ? 1.0f : 0.0f;

    const float* gb = y_pred + (size_t)b * (Tn * Cn);

    auto issue = [&](int k) {                      // my k-th chunk = global 2k+w
        const float* g = gb + (2 * k + w) * (U * Cn);
        float* l = ring[w][k & (RING - 1)];
#pragma unroll
        for (int kk = 0; kk < 4; ++kk)             // 4 x (64 lanes x 16B) = 4 KB
            dma16(g + kk * 256 + i * 4, l + kk * 256);
    };

    float ql[U], qb[U];
    auto gather = [&](int k) {
        const float* s = ring[w][k & (RING - 1)];
#pragma unroll
        for (int j = 0; j < U; ++j) {
            ql[j] = fmaf(s[j * Cn + li],    128.0f, EPS128);
            qb[j] = fmaf(s[j * Cn + BLANK], 128.0f, EPS128);
        }
    };

    float E = 0.f, O = 0.f, X = 0.f;   // states 2i, 2i+1, 128(lane63)
    int Esum = 0;

    auto steps = [&](bool first) {
#pragma unroll
        for (int j = 0; j < U; ++j) {
            if (first && j == 0) {                 // t=0: only states 0,1
                E = (i == 0) ? qb[0] : 0.f;
                O = (i == 0) ? ql[0] : 0.f;
                X = 0.f;
                continue;
            }
            const float Ol = dpp_movf<0x138>(O);   // state 2i-1 from left
            const float t1 = O + E;
            const float nO = fmaf(skf, Ol, t1) * ql[j];
            const float nE = (E + Ol) * qb[j];
            const float nX = (X + O) * qb[j];
            E = nE; O = nO; X = nX;
        }
    };
    auto renorm = [&]() {
        float m = fmaxf(E, O);
        if (i == 63) m = fmaxf(m, X);
        m = fmaxf(m, dpp_movf<0x111>(m));
        m = fmaxf(m, dpp_movf<0x112>(m));
        m = fmaxf(m, dpp_movf<0x114>(m));
        m = fmaxf(m, dpp_movf<0x118>(m));
        m = fmaxf(m, dpp_movf<0x142>(m));
        m = fmaxf(m, dpp_movf<0x143>(m));          // lane63 = wave max
        const unsigned ub =
            (unsigned)__builtin_amdgcn_readlane(__float_as_int(m), 63);
        const int eb = (int)(ub >> 23);
        const float sc = __int_as_float((unsigned)(254 - eb) << 23);
        Esum += eb - 127;
        E *= sc; O *= sc; X *= sc;
    };
    auto st_write = [&]() {
        stE[i] = E; stO[i] = O; stX[i] = X;
        if (i == 63) stS = Esum;
    };
    auto st_read = [&]() {
        E = stE[i]; O = stO[i]; X = stX[i]; Esum = stS;
    };

    // ---- prologue: each wave fills its 4-deep ring (16 loads out) ----
#pragma unroll
    for (int k = 0; k < RING; ++k) issue(k);
    if (w == 0) { WAIT_VM(12); SCHED_FENCE(); gather(0); }

    // ---- main pairs k=0..11: slot A owner w0 (chunk 2k), slot B w1 ----
    for (int k = 0; k < 12; ++k) {
        if (w == 0) {
            issue(k + 4);                          // fire loads early
            if (k > 0) st_read();
            steps(k == 0); renorm(); st_write();
        } else {
            WAIT_VM(12); SCHED_FENCE();            // my chunk k landed
            gather(k);
        }
        wave_sync();
        if (w == 1) {
            issue(k + 4);
            st_read(); steps(false); renorm(); st_write();
        } else {
            WAIT_VM(12); SCHED_FENCE();            // my chunk k+1 landed
            gather(k + 1);
        }
        wave_sync();
    }

    // ---- tail pairs 12..15 (no more issues; exact shrinking waits) ----
    // pair 12
    if (w == 0) { st_read(); steps(false); renorm(); st_write(); }
    else        { WAIT_VM(12); SCHED_FENCE(); gather(12); }
    wave_sync();
    if (w == 1) { st_read(); steps(false); renorm(); st_write(); }
    else        { WAIT_VM(8);  SCHED_FENCE(); gather(13); }
    wave_sync();
    // pair 13
    if (w == 0) { st_read(); steps(false); renorm(); st_write(); }
    else        { WAIT_VM(8);  SCHED_FENCE(); gather(13); }
    wave_sync();
    if (w == 1) { st_read(); steps(false); renorm(); st_write(); }
    else        { WAIT_VM(4);  SCHED_FENCE(); gather(14); }
    wave_sync();
    // pair 14
    if (w == 0) { st_read(); steps(false); renorm(); st_write(); }
    else        { WAIT_VM(4);  SCHED_FENCE(); gather(14); }
    wave_sync();
    if (w == 1) { st_read(); steps(false); renorm(); st_write(); }
    else        { WAIT_VM(0);  SCHED_FENCE(); gather(15); }
    wave_sync();
    // pair 15
    if (w == 0) { st_read(); steps(false); renorm(); st_write(); }
    else        { WAIT_VM(0);  SCHED_FENCE(); gather(15); }
    wave_sync();
    if (w == 1) {
        st_read();
        steps(false);                              // chunk 31 (no renorm)
        if (i == 63) {
            const float s = O + X;                 // alpha[127]+alpha[128]
#if __has_builtin(__builtin_amdgcn_logf)
            const float l2 = __builtin_amdgcn_logf(s);
#else
            const float l2 = log2f(s);
#endif
            out[b] = -(l2 + (float)(Esum - 7 * Tn)) * LN2;
        }
    }
}

extern "C" void kernel_launch(void* const* d_in, const int* in_sizes, int n_in,
                              void* d_out, int out_size, void* d_ws, size_t ws_size,
                              hipStream_t stream) {
    const int*   y_true = (const int*)d_in[0];
    const float* y_pred = (const float*)d_in[1];
    float*       out    = (float*)d_out;
    hipLaunchKernelGGL(ctc_pair_kernel, dim3(Bn), dim3(128), 0, stream,
                       y_true, y_pred, out);
}